// Round 1
// baseline (1087.822 us; speedup 1.0000x reference)
//
#include <hip/hip_runtime.h>
#include <cstdint>
#include <cstddef>

#define U_CNT 100000
#define I_CNT 50000
#define D_DIM 64
#define N_CNT (U_CNT + I_CNT)
#define NNZ_CNT 4000000
#define EPS_F 0.2f

// Column-bucketed CSR: key = row*NB + col/CHUNK. Within each row the edge
// list is grouped by ascending column bucket, so all resident waves sweep
// the same ~2.4MB x-window in the same order -> L2 hits instead of L3.
#define NB 16
#define CHUNK ((N_CNT + NB - 1) / NB)                    // 9375 rows = 2.4 MB of x
#define M_CNT (N_CNT * NB)                               // 2,400,000 keys
#define SCAN_TILE 1024
#define N_TILES2 ((M_CNT + SCAN_TILE - 1) / SCAN_TILE)   // 2344

// ---------------- CSR build: histogram over (row,bucket) keys ----------------
__global__ void hist_kernel(const int* __restrict__ rows, const int* __restrict__ cols,
                            int* __restrict__ deg) {
    int t = blockIdx.x * blockDim.x + threadIdx.x;
    if (t >= NNZ_CNT / 4) return;
    int4 r4 = ((const int4*)rows)[t];
    int4 c4 = ((const int4*)cols)[t];
    atomicAdd(&deg[r4.x * NB + c4.x / CHUNK], 1);
    atomicAdd(&deg[r4.y * NB + c4.y / CHUNK], 1);
    atomicAdd(&deg[r4.z * NB + c4.z / CHUNK], 1);
    atomicAdd(&deg[r4.w * NB + c4.w / CHUNK], 1);
}

// ---------------- hierarchical scan, stage 1: per-tile scan ----------------
// Scans deg into rowptr (tile-local exclusive), writes tile total, and ZEROES
// deg so it can be reused as the scatter cursor.
__global__ __launch_bounds__(256) void partial_scan_kernel(
    int* __restrict__ deg, int* __restrict__ rowptr, int* __restrict__ tileSums) {
    __shared__ int lds[256];
    const int t = threadIdx.x;
    const int gbase = blockIdx.x * SCAN_TILE + t * 4;
    int v[4];
    int s = 0;
    #pragma unroll
    for (int j = 0; j < 4; ++j) {
        int i = gbase + j;
        v[j] = (i < M_CNT) ? deg[i] : 0;
        if (i < M_CNT) deg[i] = 0;
        s += v[j];
    }
    lds[t] = s;
    __syncthreads();
    for (int off = 1; off < 256; off <<= 1) {
        int x = (t >= off) ? lds[t - off] : 0;
        __syncthreads();
        lds[t] += x;
        __syncthreads();
    }
    int ex = (t > 0) ? lds[t - 1] : 0;
    #pragma unroll
    for (int j = 0; j < 4; ++j) {
        int i = gbase + j;
        if (i < M_CNT) rowptr[i] = ex;
        ex += v[j];
    }
    if (t == 255) tileSums[blockIdx.x] = lds[255];
}

// ---------------- stage 2: scan tile sums (2344, single block, 3 chunks) ----
__global__ __launch_bounds__(256) void scan_sums_kernel(
    const int* __restrict__ tileSums, int* __restrict__ tileOffs,
    int* __restrict__ rowptr) {
    __shared__ int lds[256];
    const int t = threadIdx.x;
    int carry = 0;
    for (int base = 0; base < N_TILES2; base += SCAN_TILE) {
        int v[4];
        int s = 0;
        #pragma unroll
        for (int j = 0; j < 4; ++j) {
            int i = base + t * 4 + j;
            v[j] = (i < N_TILES2) ? tileSums[i] : 0;
            s += v[j];
        }
        lds[t] = s;
        __syncthreads();
        for (int off = 1; off < 256; off <<= 1) {
            int x = (t >= off) ? lds[t - off] : 0;
            __syncthreads();
            lds[t] += x;
            __syncthreads();
        }
        int ex = carry + ((t > 0) ? lds[t - 1] : 0);
        #pragma unroll
        for (int j = 0; j < 4; ++j) {
            int i = base + t * 4 + j;
            if (i < N_TILES2) tileOffs[i] = ex;
            ex += v[j];
        }
        carry += lds[255];
        __syncthreads();
    }
    if (t == 0) rowptr[M_CNT] = carry;
}

// ---------------- stage 3: add tile offsets ----------------
__global__ __launch_bounds__(256) void add_offs_kernel(
    int* __restrict__ rowptr, const int* __restrict__ tileOffs) {
    const int off = tileOffs[blockIdx.x];
    const int gbase = blockIdx.x * SCAN_TILE + threadIdx.x * 4;
    #pragma unroll
    for (int j = 0; j < 4; ++j) {
        int i = gbase + j;
        if (i < M_CNT) rowptr[i] += off;
    }
}

// ---------------- CSR build: scatter packed (col,val), 4 edges/thread ------
__global__ void scatter_kernel(const int* __restrict__ rows, const int* __restrict__ cols,
                               const float* __restrict__ vals,
                               const int* __restrict__ rowptr, int* __restrict__ cursor,
                               int2* __restrict__ cpack) {
    int t = blockIdx.x * blockDim.x + threadIdx.x;
    if (t >= NNZ_CNT / 4) return;
    int4   r4 = ((const int4*)rows)[t];
    int4   c4 = ((const int4*)cols)[t];
    float4 v4 = ((const float4*)vals)[t];
    int k, p;
    k = r4.x * NB + c4.x / CHUNK;
    p = rowptr[k] + atomicAdd(&cursor[k], 1); cpack[p] = make_int2(c4.x, __float_as_int(v4.x));
    k = r4.y * NB + c4.y / CHUNK;
    p = rowptr[k] + atomicAdd(&cursor[k], 1); cpack[p] = make_int2(c4.y, __float_as_int(v4.y));
    k = r4.z * NB + c4.z / CHUNK;
    p = rowptr[k] + atomicAdd(&cursor[k], 1); cpack[p] = make_int2(c4.z, __float_as_int(v4.z));
    k = r4.w * NB + c4.w / CHUNK;
    p = rowptr[k] + atomicAdd(&cursor[k], 1); cpack[p] = make_int2(c4.w, __float_as_int(v4.w));
}

__device__ __forceinline__ float sgnf(float x) {
    return (x > 0.f) ? 1.f : ((x < 0.f) ? -1.f : 0.f);
}

// ---------------- fused SpMM + noise + accumulate ----------------
// 16 lanes per row (each lane owns a float4 of D=64); 4 rows per wave,
// 16 rows per 256-thread block. Edge metadata read group-uniformly.
// Row r's edges span [rowptr[r*NB], rowptr[(r+1)*NB]) -- bucket-ordered.
// MODE 0: gather from (ue,ie) split; xnext = ego; acc_out = ego   (layer 0)
// MODE 1: gather from xin;          xnext = ego; acc_out += ego   (layer 1)
// MODE 2: gather from xin;          acc_out = (acc_out + ego)/3   (layer 2)
template <int MODE>
__global__ __launch_bounds__(256) void layer_kernel(
    const int* __restrict__ rowptr, const int2* __restrict__ cpack,
    const float4* __restrict__ xin, const float4* __restrict__ ue4,
    const float4* __restrict__ ie4,
    const float4* __restrict__ noise_k, float4* __restrict__ xnext,
    float4* __restrict__ acc_out) {
    const int gl = threadIdx.x & 15;                 // lane within 16-lane row group
    const int r  = blockIdx.x * 16 + (threadIdx.x >> 4);
    if (r >= N_CNT) return;
    const int start = rowptr[r * NB];
    const int end   = rowptr[r * NB + NB];

    float4 acc = make_float4(0.f, 0.f, 0.f, 0.f);
    #pragma unroll 4
    for (int e = start; e < end; ++e) {
        int2 p = cpack[e];                            // group-uniform 8B load
        float vj = __int_as_float(p.y);
        const float4* xb;
        if (MODE == 0) {
            xb = (p.x < U_CNT) ? (ue4 + (size_t)p.x * 16)
                               : (ie4 + (size_t)(p.x - U_CNT) * 16);
        } else {
            xb = xin + (size_t)p.x * 16;
        }
        float4 xr = xb[gl];                           // 256B/row, coalesced over 16 lanes
        acc.x += vj * xr.x;
        acc.y += vj * xr.y;
        acc.z += vj * xr.z;
        acc.w += vj * xr.w;
    }

    // normalized noise (norm over the row's 64 features = 16 lanes x 4 comps)
    float4 nz = noise_k[(size_t)r * 16 + gl];
    float sq = nz.x * nz.x + nz.y * nz.y + nz.z * nz.z + nz.w * nz.w;
    #pragma unroll
    for (int off = 8; off > 0; off >>= 1) sq += __shfl_xor(sq, off);
    float inv = EPS_F / fmaxf(sqrtf(sq), 1e-12f);

    float4 ego;
    ego.x = acc.x + sgnf(acc.x) * nz.x * inv;
    ego.y = acc.y + sgnf(acc.y) * nz.y * inv;
    ego.z = acc.z + sgnf(acc.z) * nz.z * inv;
    ego.w = acc.w + sgnf(acc.w) * nz.w * inv;

    size_t oi = (size_t)r * 16 + gl;
    if (MODE == 0) {
        xnext[oi] = ego;
        acc_out[oi] = ego;
    } else if (MODE == 1) {
        xnext[oi] = ego;
        float4 a = acc_out[oi];
        a.x += ego.x; a.y += ego.y; a.z += ego.z; a.w += ego.w;
        acc_out[oi] = a;
    } else {
        float4 a = acc_out[oi];
        a.x = (a.x + ego.x) * (1.f / 3.f);
        a.y = (a.y + ego.y) * (1.f / 3.f);
        a.z = (a.z + ego.z) * (1.f / 3.f);
        a.w = (a.w + ego.w) * (1.f / 3.f);
        acc_out[oi] = a;
    }
}

extern "C" void kernel_launch(void* const* d_in, const int* in_sizes, int n_in,
                              void* d_out, int out_size, void* d_ws, size_t ws_size,
                              hipStream_t stream) {
    const float* ue    = (const float*)d_in[0];
    const float* ie    = (const float*)d_in[1];
    const int*   rows  = (const int*)d_in[2];
    const int*   cols  = (const int*)d_in[3];
    const float* vals  = (const float*)d_in[4];
    const float* noise = (const float*)d_in[5];
    float* out = (float*)d_out;
    char*  ws  = (char*)d_ws;

    auto align16 = [](size_t x) { return (x + 15) & ~(size_t)15; };
    size_t off = 0;
    int*   rowptr2  = (int*)(ws + off);  off = align16(off + (size_t)(M_CNT + 1) * 4);
    int*   tileSums = (int*)(ws + off);  off = align16(off + (size_t)N_TILES2 * 4);
    int*   tileOffs = (int*)(ws + off);  off = align16(off + (size_t)N_TILES2 * 4);
    int2*  cpack    = (int2*)(ws + off); off = align16(off + (size_t)NNZ_CNT * 8);
    float* bufA     = (float*)(ws + off); off += (size_t)N_CNT * D_DIM * 4;
    // cursor/deg (9.6 MB) aliases bufA: build finishes before layer 1 writes bufA.
    int*   deg2     = (int*)bufA;
    (void)ws_size; (void)in_sizes; (void)n_in; (void)out_size;

    const size_t ND = (size_t)N_CNT * D_DIM;
    float* cl = out + ND;  // ego_cl region; doubles as layer-0 output / layer-1 input

    // CSR build (column-bucketed keys)
    hipMemsetAsync(deg2, 0, (size_t)M_CNT * 4, stream);
    hist_kernel<<<(NNZ_CNT / 4 + 255) / 256, 256, 0, stream>>>(rows, cols, deg2);
    partial_scan_kernel<<<N_TILES2, 256, 0, stream>>>(deg2, rowptr2, tileSums);  // zeroes deg2
    scan_sums_kernel<<<1, 256, 0, stream>>>(tileSums, tileOffs, rowptr2);
    add_offs_kernel<<<N_TILES2, 256, 0, stream>>>(rowptr2, tileOffs);
    scatter_kernel<<<(NNZ_CNT / 4 + 255) / 256, 256, 0, stream>>>(rows, cols, vals, rowptr2,
                                                                  deg2, cpack);

    // 3 propagation layers (fused spmm + noise + accumulate), 16 rows/block
    int blocks = (N_CNT + 15) / 16;
    layer_kernel<0><<<blocks, 256, 0, stream>>>(rowptr2, cpack, nullptr,
                                                (const float4*)ue, (const float4*)ie,
                                                (const float4*)(noise + 0 * ND),
                                                (float4*)cl, (float4*)out);
    layer_kernel<1><<<blocks, 256, 0, stream>>>(rowptr2, cpack, (const float4*)cl,
                                                nullptr, nullptr,
                                                (const float4*)(noise + 1 * ND),
                                                (float4*)bufA, (float4*)out);
    layer_kernel<2><<<blocks, 256, 0, stream>>>(rowptr2, cpack, (const float4*)bufA,
                                                nullptr, nullptr,
                                                (const float4*)(noise + 2 * ND),
                                                nullptr, (float4*)out);
}